// Round 22
// baseline (59.211 us; speedup 1.0000x reference)
//
#include <hip/hip_runtime.h>

// ---------------------------------------------------------------------------
// AttentionHead: GroupNorm -> QKV 1x1 conv -> softmax attention -> 1x1 conv.
// Round 22: fused barrier-free attn at 4 waves/SIMD. 512-thr blocks, 32
// q-rows each (grid 512 = 2 blocks/CU). Per wave: m-eighth, 16 tiles of 32m,
// SINGLE 8KB LDS buffer with register-bridged double buffering: ds_read all
// frags to regs -> lgkmcnt(0) (buffer dead) -> issue next tile's gload_lds
// into the SAME buffer -> compute from regs -> vmcnt(0). 64KB LDS/block,
// VGPR<=128 (single-subtile body). Fused f32 merge + projection epilogue.
// gn_stats / gn_qkv byte-identical to r19-verified.
// ---------------------------------------------------------------------------

#define B_ 4
#define C_ 64
#define D_ 64
#define N_ 4096

using bf16x8 = __attribute__((ext_vector_type(8))) short;     // 8 bf16 = 4 VGPR
using u16x8  = __attribute__((ext_vector_type(8))) unsigned short;
using u32x4  = __attribute__((ext_vector_type(4))) unsigned int;
using f32x16 = __attribute__((ext_vector_type(16))) float;

// round-to-nearest-even f32 -> bf16 bits
__device__ __forceinline__ unsigned short f2bf(float f) {
    unsigned u = __builtin_bit_cast(unsigned, f);
    u = (u + 0x7FFFu + ((u >> 16) & 1u)) >> 16;
    return (unsigned short)u;
}

// single-instruction exp2: builtin (backend-hazard-managed) or asm + s_nop
#if __has_builtin(__builtin_amdgcn_exp2f)
__device__ __forceinline__ float fast_exp2(float x) {
    return __builtin_amdgcn_exp2f(x);
}
#else
__device__ __forceinline__ float fast_exp2(float x) {
    float r;
    asm volatile("v_exp_f32 %0, %1\n\ts_nop 1" : "=v"(r) : "v"(x));
    return r;
}
#endif

// async global->LDS, 16B per lane (lds dst wave-uniform base, +lane*16)
__device__ __forceinline__ void gload16(const void* g, void* l) {
    __builtin_amdgcn_global_load_lds(
        (const __attribute__((address_space(1))) unsigned int*)g,
        (__attribute__((address_space(3))) unsigned int*)l, 16, 0, 0);
}

// ---------------------------------------------------------------------------
// Kernel 1: per-(b,c) mean / rsqrt(var+eps) over H*W = 4096
// ---------------------------------------------------------------------------
__global__ __launch_bounds__(1024)
void gn_stats_kernel(const float* __restrict__ x, float* __restrict__ stats) {
    __shared__ float red[32];
    const int bx  = blockIdx.x;
    const int tid = threadIdx.x;
    const float4* xp = (const float4*)(x + (size_t)bx * N_);
    float4 v = xp[tid];
    float s = (v.x + v.y) + (v.z + v.w);
    float q = (v.x * v.x + v.y * v.y) + (v.z * v.z + v.w * v.w);
#pragma unroll
    for (int off = 1; off < 64; off <<= 1) {
        s += __shfl_xor(s, off);
        q += __shfl_xor(q, off);
    }
    const int w = tid >> 6;
    if ((tid & 63) == 0) { red[w * 2] = s; red[w * 2 + 1] = q; }
    __syncthreads();
    if (w == 0) {
        const int lane = tid & 63;
        float sl = (lane < 16) ? red[lane * 2] : 0.f;
        float ql = (lane < 16) ? red[lane * 2 + 1] : 0.f;
#pragma unroll
        for (int off = 1; off < 16; off <<= 1) {
            sl += __shfl_xor(sl, off);
            ql += __shfl_xor(ql, off);
        }
        if (lane == 0) {
            float mu  = sl * (1.f / 4096.f);
            float var = ql * (1.f / 4096.f) - mu * mu;
            var = fmaxf(var, 0.f);
            stats[bx * 2]     = mu;
            stats[bx * 2 + 1] = 1.f / sqrtf(var + 1e-5f);
        }
    }
}

// ---------------------------------------------------------------------------
// Kernel 2: GroupNorm apply + QKV projections -> MFMA-frag layouts (r7).
// ---------------------------------------------------------------------------
__global__ __launch_bounds__(512)
void gn_qkv_kernel(const float* __restrict__ x, const float* __restrict__ stats,
                   const float* __restrict__ gnw, const float* __restrict__ gnb,
                   const float* __restrict__ wq, const float* __restrict__ bq,
                   const float* __restrict__ wk, const float* __restrict__ bk,
                   const float* __restrict__ wv, const float* __restrict__ bv,
                   unsigned short* __restrict__ Qt, unsigned short* __restrict__ Kf,
                   unsigned short* __restrict__ Vf) {
    __shared__ float xn[64 * 64];                 // [c][n] 16 KB
    __shared__ __align__(16) char vs[64 * 128];   // [m][d] bf16, XOR-swizzled, 8 KB
    const int t  = threadIdx.x;
    const int bx = blockIdx.x;
    const int b  = bx >> 6;
    const int n0 = (bx & 63) * 64;

    // ---- Phase A: load + normalize x tile ----
    {
        const int c  = t >> 3;
        const int nc = (t & 7) * 8;
        const float* xp = x + (size_t)(b * 64 + c) * N_ + n0 + nc;
        float4 xa = *(const float4*)(xp);
        float4 xb = *(const float4*)(xp + 4);
        float mu = stats[(b * 64 + c) * 2];
        float rs = stats[(b * 64 + c) * 2 + 1];
        float gw = gnw[c] * rs;
        float gb = gnb[c] - mu * gw;
        float* xr = xn + c * 64 + nc;
        xr[0] = xa.x * gw + gb; xr[1] = xa.y * gw + gb;
        xr[2] = xa.z * gw + gb; xr[3] = xa.w * gw + gb;
        xr[4] = xb.x * gw + gb; xr[5] = xb.y * gw + gb;
        xr[6] = xb.z * gw + gb; xr[7] = xb.w * gw + gb;
    }
    __syncthreads();

    // ---- Phase B: per (n, 8d) dot products ----
    const int n    = t & 63;
    const int dblk = __builtin_amdgcn_readfirstlane(t >> 6);
    const int d0   = dblk * 8;

    float aq[8], ak[8], av[8];
#pragma unroll
    for (int i = 0; i < 8; ++i) { aq[i] = 0.f; ak[i] = 0.f; av[i] = 0.f; }

#pragma unroll 4
    for (int c = 0; c < 64; ++c) {
        const float xv = xn[c * 64 + n];
#pragma unroll
        for (int i = 0; i < 8; ++i) {
            aq[i] += wq[(d0 + i) * 64 + c] * xv;
            ak[i] += wk[(d0 + i) * 64 + c] * xv;
            av[i] += wv[(d0 + i) * 64 + c] * xv;
        }
    }

    const float QS = 0.18033688011112042f;  // 0.125 * log2(e): exp2-domain logits
    const int m = n0 + n;
    u16x8 qv, kv, vb;
#pragma unroll
    for (int i = 0; i < 8; ++i) {
        qv[i] = f2bf((aq[i] + bq[d0 + i]) * QS);
        kv[i] = f2bf(ak[i] + bk[d0 + i]);
        vb[i] = f2bf(av[i] + bv[d0 + i]);
    }
    // Q: [n][d] row store (16B)
    *(u16x8*)(Qt + ((size_t)(b * N_ + m)) * 64 + d0) = qv;
    // K: direct frag store
    {
        const int kc = dblk >> 1, h = dblk & 1, mt = m >> 5;
        *(u16x8*)(Kf + ((size_t)((b * 128 + mt) * 4 + kc)) * 512
                     + (h * 32 + (m & 31)) * 8) = kv;
    }
    // V: swizzled LDS stage
    *(u16x8*)(vs + n * 128 + ((dblk * 16) ^ ((n & 7) << 4))) = vb;
    __syncthreads();

    // ---- Phase C: frag-ordered Vf copyout (one 16B store per thread) ----
    {
        const int mc_l = t >> 7;            // 0..3
        const int dt   = (t >> 6) & 1;
        const int lp   = t & 63;
        const int hp   = lp >> 5;
        const int dcol = (lp & 31) + dt * 32;
        const int cbase = (dcol & ~7) * 2;
        const int clow  = (dcol & 7) * 2;
        u16x8 tmp;
#pragma unroll
        for (int j = 0; j < 8; ++j) {
            const int ml = mc_l * 16 + hp * 8 + j;   // ml&7 == j
            tmp[j] = *(const unsigned short*)(
                vs + ml * 128 + (cbase ^ (j << 4)) + clow);
        }
        *(u16x8*)(Vf + ((size_t)((b * 256 + (n0 >> 4) + mc_l) * 2 + dt)) * 512
                     + lp * 8) = tmp;
    }
}

// ---------------------------------------------------------------------------
// Kernel 3: attention + fused projection; 8 waves, 32 q-rows, barrier-free.
// grid = 512 blocks (b = bid&3, qc = bid>>2: 32 q-rows), 512 thr (8 waves),
// 2 blocks/CU = 4 waves/SIMD. Wave wvu: m-eighth [wvu*512, +512), 16 tiles
// of 32 m through a SINGLE 8KB LDS buffer, register-bridged: ds_read frags
// -> lgkmcnt(0) -> issue next tile's gload_lds into same buffer -> compute
// -> vmcnt(0). Epilogue: two-stage f32 merge, invl, atile, 512-thr project.
// ---------------------------------------------------------------------------
__global__ __launch_bounds__(512, 2)
void attn_kernel(const unsigned short* __restrict__ Qt,
                 const unsigned short* __restrict__ Kf,
                 const unsigned short* __restrict__ Vf,
                 const float* __restrict__ wo, const float* __restrict__ bo,
                 float* __restrict__ out) {
    __shared__ __align__(16) char smem[65536];
    const int tid  = threadIdx.x;
    const int lane = tid & 63;
    const int wvu  = __builtin_amdgcn_readfirstlane(tid >> 6);   // m-eighth 0..7
    const int c    = lane & 31;
    const int h    = lane >> 5;
    const int bid  = blockIdx.x;
    const int b    = bid & 3;
    const int qc   = bid >> 2;      // 0..127
    const int n0   = qc * 32;

    // Q B-frag: lane (q=c, h) holds Q[n0+c][kc*16 + h*8 + j]
    const unsigned short* qp = Qt + (size_t)(b * N_ + n0 + c) * 64 + h * 8;
    bf16x8 qa[4];
#pragma unroll
    for (int kc = 0; kc < 4; ++kc) qa[kc] = *(const bf16x8*)(qp + kc * 16);

    f32x16 oacc0, oacc1;
#pragma unroll
    for (int i = 0; i < 16; ++i) { oacc0[i] = 0.f; oacc1[i] = 0.f; }
    float ls0 = 0.f, ls1 = 0.f;

    const int lof = lane * 16;
    char* sbase = smem + wvu * 8192;    // single buffer: K 4KB | V 4KB
    const char* kTn = (const char*)Kf + (size_t)b * 524288 + (size_t)wvu * 65536;
    const char* vTn = (const char*)Vf + (size_t)b * 524288 + (size_t)wvu * 65536;

    // ---- prologue: stage tile 0 ----
#pragma unroll
    for (int j = 0; j < 4; ++j) {
        gload16(kTn + j * 1024 + lof, sbase + j * 1024);
        gload16(vTn + j * 1024 + lof, sbase + 4096 + j * 1024);
    }
    asm volatile("s_waitcnt vmcnt(0)" ::: "memory");
    __builtin_amdgcn_sched_barrier(0);

    for (int t = 0; t < 16; ++t) {
        // ---- pull current tile's frags into registers ----
        const char* kb = sbase + lof;
        bf16x8 kf0 = *(const bf16x8*)(kb);
        bf16x8 kf1 = *(const bf16x8*)(kb + 1024);
        bf16x8 kf2 = *(const bf16x8*)(kb + 2048);
        bf16x8 kf3 = *(const bf16x8*)(kb + 3072);
        const char* vbp = sbase + 4096 + lof;
        bf16x8 vf0 = *(const bf16x8*)(vbp);
        bf16x8 vf1 = *(const bf16x8*)(vbp + 1024);
        bf16x8 vf2 = *(const bf16x8*)(vbp + 2048);
        bf16x8 vf3 = *(const bf16x8*)(vbp + 3072);
        asm volatile("s_waitcnt lgkmcnt(0)" ::: "memory");   // buffer now dead
        __builtin_amdgcn_sched_barrier(0);

        // ---- issue next tile's async stage into the SAME buffer ----
        if (t + 1 < 16) {
            kTn += 4096;
            vTn += 4096;
#pragma unroll
            for (int j = 0; j < 4; ++j) {
                gload16(kTn + j * 1024 + lof, sbase + j * 1024);
                gload16(vTn + j * 1024 + lof, sbase + 4096 + j * 1024);
            }
        }

        // ---- compute from registers (loads fly underneath) ----
        f32x16 sa;
#pragma unroll
        for (int i = 0; i < 16; ++i) sa[i] = 0.f;
        sa = __builtin_amdgcn_mfma_f32_32x32x16_bf16(kf0, qa[0], sa, 0, 0, 0);
        sa = __builtin_amdgcn_mfma_f32_32x32x16_bf16(kf1, qa[1], sa, 0, 0, 0);
        sa = __builtin_amdgcn_mfma_f32_32x32x16_bf16(kf2, qa[2], sa, 0, 0, 0);
        sa = __builtin_amdgcn_mfma_f32_32x32x16_bf16(kf3, qa[3], sa, 0, 0, 0);

        // P = exp2(S^T); 2 independent sum chains
#pragma unroll
        for (int i = 0; i < 16; i += 2) {
            float p0 = fast_exp2(sa[i]);
            float p1 = fast_exp2(sa[i + 1]);
            sa[i] = p0; sa[i + 1] = p1;
            ls0 += p0; ls1 += p1;
        }
        // pack to bf16 pairs (consecutive m rows) and swap halves
        unsigned dw[8];
#pragma unroll
        for (int i = 0; i < 8; ++i)
            asm("v_cvt_pk_bf16_f32 %0, %1, %2"
                : "=v"(dw[i]) : "v"(sa[2 * i]), "v"(sa[2 * i + 1]));
        asm("v_permlane32_swap_b32 %0, %1" : "+v"(dw[0]), "+v"(dw[2]));
        asm("v_permlane32_swap_b32 %0, %1" : "+v"(dw[1]), "+v"(dw[3]));
        asm("v_permlane32_swap_b32 %0, %1" : "+v"(dw[4]), "+v"(dw[6]));
        asm("v_permlane32_swap_b32 %0, %1" : "+v"(dw[5]), "+v"(dw[7]));
        bf16x8 pf0 = __builtin_bit_cast(bf16x8, (u32x4){dw[0], dw[1], dw[2], dw[3]});
        bf16x8 pf1 = __builtin_bit_cast(bf16x8, (u32x4){dw[4], dw[5], dw[6], dw[7]});

        oacc0 = __builtin_amdgcn_mfma_f32_32x32x16_bf16(vf0, pf0, oacc0, 0, 0, 0);
        oacc1 = __builtin_amdgcn_mfma_f32_32x32x16_bf16(vf1, pf0, oacc1, 0, 0, 0);
        oacc0 = __builtin_amdgcn_mfma_f32_32x32x16_bf16(vf2, pf1, oacc0, 0, 0, 0);
        oacc1 = __builtin_amdgcn_mfma_f32_32x32x16_bf16(vf3, pf1, oacc1, 0, 0, 0);

        // next tile's staging must have landed before its ds_reads
        asm volatile("s_waitcnt vmcnt(0)" ::: "memory");
        __builtin_amdgcn_sched_barrier(0);
    }

    // per-wave rowsum (col q = own half + other half)
    float lsum = ls0 + ls1;
    float rs = lsum + __shfl_xor(lsum, 32);

    // ---- epilogue: two-stage f32 merge, normalize, in-block projection ----
    __syncthreads();                          // all streams dead; LDS reusable
    float* lsm   = (float*)(smem + 32768);    // [8 wave][32 q]
    float* invl  = (float*)(smem + 33792);    // [32]
    float* atile = (float*)(smem + 33920);    // [64 d][33] f32
    if (wvu < 4) {                            // stage A: waves 0-3 write
        float* mrg = (float*)(smem + wvu * 8192);   // [64 d][32 q]
#pragma unroll
        for (int r = 0; r < 16; ++r) {
            const int row = (r & 3) + 8 * (r >> 2) + 4 * h;
            mrg[row * 32 + c]        = oacc0[r];
            mrg[(row + 32) * 32 + c] = oacc1[r];
        }
    }
    if (h == 0) lsm[wvu * 32 + c] = rs;
    __syncthreads();
    if (wvu >= 4) {                           // stage B: waves 4-7 add
        float* mrg = (float*)(smem + (wvu - 4) * 8192);
#pragma unroll
        for (int r = 0; r < 16; ++r) {
            const int row = (r & 3) + 8 * (r >> 2) + 4 * h;
            mrg[row * 32 + c]        += oacc0[r];
            mrg[(row + 32) * 32 + c] += oacc1[r];
        }
    }
    if (tid < 32) {
        // lsm not complete until the barrier below; compute after it instead
    }
    __syncthreads();
    if (tid < 32) {
        float lt = 0.f;
#pragma unroll
        for (int k = 0; k < 8; ++k) lt += lsm[k * 32 + tid];
        invl[tid] = 1.f / lt;
    }
    __syncthreads();
    {   // merge 4 buffers + normalize -> atile (2048 elems / 512 thr)
        const float* m0 = (const float*)smem;
#pragma unroll
        for (int k = 0; k < 4; ++k) {
            const int idx = k * 512 + tid;
            const int d   = idx >> 5;
            const int q   = idx & 31;
            float sum = (m0[idx] + m0[2048 + idx])
                      + (m0[4096 + idx] + m0[6144 + idx]);
            atile[d * 33 + q] = sum * invl[q];
        }
    }
    __syncthreads();
    {   // projection: thread (q = tid&31, e0 = (tid>>5)*4)
        const int q  = tid & 31;
        const int e0 = (tid >> 5) * 4;
        float acc[4];
#pragma unroll
        for (int i = 0; i < 4; ++i) acc[i] = bo[e0 + i];
#pragma unroll 8
        for (int d = 0; d < 64; ++d) {
            const float xv = atile[d * 33 + q];
#pragma unroll
            for (int i = 0; i < 4; ++i) acc[i] += wo[(e0 + i) * 64 + d] * xv;
        }
#pragma unroll
        for (int i = 0; i < 4; ++i)
            out[((size_t)(b * 64 + e0 + i) << 12) + n0 + q] = acc[i];
    }
}

// ---------------------------------------------------------------------------
extern "C" void kernel_launch(void* const* d_in, const int* in_sizes, int n_in,
                              void* d_out, int out_size, void* d_ws, size_t ws_size,
                              hipStream_t stream) {
    const float* x   = (const float*)d_in[0];
    const float* gnw = (const float*)d_in[1];
    const float* gnb = (const float*)d_in[2];
    const float* wq  = (const float*)d_in[3];
    const float* bq  = (const float*)d_in[4];
    const float* wk  = (const float*)d_in[5];
    const float* bk  = (const float*)d_in[6];
    const float* wv  = (const float*)d_in[7];
    const float* bv  = (const float*)d_in[8];
    const float* wo  = (const float*)d_in[9];
    const float* bo  = (const float*)d_in[10];
    float* out = (float*)d_out;

    char* wsb = (char*)d_ws;
    float*          stats = (float*)wsb;                                  //   2 KB
    unsigned short* Qt    = (unsigned short*)(wsb + 2048);                //   2 MB
    unsigned short* Kf    = (unsigned short*)(wsb + 2048 + 2097152);      //   2 MB
    unsigned short* Vf    = (unsigned short*)(wsb + 2048 + 2 * 2097152);  //   2 MB

    gn_stats_kernel<<<dim3(B_ * C_), dim3(1024), 0, stream>>>(x, stats);
    gn_qkv_kernel<<<dim3(B_ * 64), dim3(512), 0, stream>>>(
        x, stats, gnw, gnb, wq, bq, wk, bk, wv, bv, Qt, Kf, Vf);
    attn_kernel<<<dim3(B_ * 128), dim3(512), 0, stream>>>(
        Qt, Kf, Vf, wo, bo, out);
}

// Round 23
// 56.142 us; speedup vs baseline: 1.0547x; 1.0547x over previous
//
#include <hip/hip_runtime.h>

// ---------------------------------------------------------------------------
// AttentionHead: GroupNorm -> QKV 1x1 conv -> softmax attention -> 1x1 conv.
// FINAL (r21-verified, 56.1us): 3 dispatches. Fused attn+projection with
// barrier-free main loop: 8 waves/block, each wave owns an m-eighth with a
// private 16KB double-buffered K/V LDS stream staged via global_load_lds
// (per-wave s_waitcnt vmcnt(0); no block barriers in the loop). In-register
// softmax (exp2-domain logits, cvt_pk_bf16 + permlane32_swap for PV frags),
// two-stage f32 LDS merge + normalize + in-block output projection.
// gn_stats / gn_qkv r7/r19-verified.
// ---------------------------------------------------------------------------

#define B_ 4
#define C_ 64
#define D_ 64
#define N_ 4096

using bf16x8 = __attribute__((ext_vector_type(8))) short;     // 8 bf16 = 4 VGPR
using u16x8  = __attribute__((ext_vector_type(8))) unsigned short;
using u32x4  = __attribute__((ext_vector_type(4))) unsigned int;
using f32x16 = __attribute__((ext_vector_type(16))) float;

// round-to-nearest-even f32 -> bf16 bits
__device__ __forceinline__ unsigned short f2bf(float f) {
    unsigned u = __builtin_bit_cast(unsigned, f);
    u = (u + 0x7FFFu + ((u >> 16) & 1u)) >> 16;
    return (unsigned short)u;
}

// single-instruction exp2: builtin (backend-hazard-managed) or asm + s_nop
#if __has_builtin(__builtin_amdgcn_exp2f)
__device__ __forceinline__ float fast_exp2(float x) {
    return __builtin_amdgcn_exp2f(x);
}
#else
__device__ __forceinline__ float fast_exp2(float x) {
    float r;
    asm volatile("v_exp_f32 %0, %1\n\ts_nop 1" : "=v"(r) : "v"(x));
    return r;
}
#endif

// async global->LDS, 16B per lane (lds dst wave-uniform base, +lane*16)
__device__ __forceinline__ void gload16(const void* g, void* l) {
    __builtin_amdgcn_global_load_lds(
        (const __attribute__((address_space(1))) unsigned int*)g,
        (__attribute__((address_space(3))) unsigned int*)l, 16, 0, 0);
}

// ---------------------------------------------------------------------------
// Kernel 1: per-(b,c) mean / rsqrt(var+eps) over H*W = 4096
// ---------------------------------------------------------------------------
__global__ __launch_bounds__(1024)
void gn_stats_kernel(const float* __restrict__ x, float* __restrict__ stats) {
    __shared__ float red[32];
    const int bx  = blockIdx.x;
    const int tid = threadIdx.x;
    const float4* xp = (const float4*)(x + (size_t)bx * N_);
    float4 v = xp[tid];
    float s = (v.x + v.y) + (v.z + v.w);
    float q = (v.x * v.x + v.y * v.y) + (v.z * v.z + v.w * v.w);
#pragma unroll
    for (int off = 1; off < 64; off <<= 1) {
        s += __shfl_xor(s, off);
        q += __shfl_xor(q, off);
    }
    const int w = tid >> 6;
    if ((tid & 63) == 0) { red[w * 2] = s; red[w * 2 + 1] = q; }
    __syncthreads();
    if (w == 0) {
        const int lane = tid & 63;
        float sl = (lane < 16) ? red[lane * 2] : 0.f;
        float ql = (lane < 16) ? red[lane * 2 + 1] : 0.f;
#pragma unroll
        for (int off = 1; off < 16; off <<= 1) {
            sl += __shfl_xor(sl, off);
            ql += __shfl_xor(ql, off);
        }
        if (lane == 0) {
            float mu  = sl * (1.f / 4096.f);
            float var = ql * (1.f / 4096.f) - mu * mu;
            var = fmaxf(var, 0.f);
            stats[bx * 2]     = mu;
            stats[bx * 2 + 1] = 1.f / sqrtf(var + 1e-5f);
        }
    }
}

// ---------------------------------------------------------------------------
// Kernel 2: GroupNorm apply + QKV projections -> MFMA-frag layouts (r7).
// ---------------------------------------------------------------------------
__global__ __launch_bounds__(512)
void gn_qkv_kernel(const float* __restrict__ x, const float* __restrict__ stats,
                   const float* __restrict__ gnw, const float* __restrict__ gnb,
                   const float* __restrict__ wq, const float* __restrict__ bq,
                   const float* __restrict__ wk, const float* __restrict__ bk,
                   const float* __restrict__ wv, const float* __restrict__ bv,
                   unsigned short* __restrict__ Qt, unsigned short* __restrict__ Kf,
                   unsigned short* __restrict__ Vf) {
    __shared__ float xn[64 * 64];                 // [c][n] 16 KB
    __shared__ __align__(16) char vs[64 * 128];   // [m][d] bf16, XOR-swizzled, 8 KB
    const int t  = threadIdx.x;
    const int bx = blockIdx.x;
    const int b  = bx >> 6;
    const int n0 = (bx & 63) * 64;

    // ---- Phase A: load + normalize x tile ----
    {
        const int c  = t >> 3;
        const int nc = (t & 7) * 8;
        const float* xp = x + (size_t)(b * 64 + c) * N_ + n0 + nc;
        float4 xa = *(const float4*)(xp);
        float4 xb = *(const float4*)(xp + 4);
        float mu = stats[(b * 64 + c) * 2];
        float rs = stats[(b * 64 + c) * 2 + 1];
        float gw = gnw[c] * rs;
        float gb = gnb[c] - mu * gw;
        float* xr = xn + c * 64 + nc;
        xr[0] = xa.x * gw + gb; xr[1] = xa.y * gw + gb;
        xr[2] = xa.z * gw + gb; xr[3] = xa.w * gw + gb;
        xr[4] = xb.x * gw + gb; xr[5] = xb.y * gw + gb;
        xr[6] = xb.z * gw + gb; xr[7] = xb.w * gw + gb;
    }
    __syncthreads();

    // ---- Phase B: per (n, 8d) dot products ----
    const int n    = t & 63;
    const int dblk = __builtin_amdgcn_readfirstlane(t >> 6);
    const int d0   = dblk * 8;

    float aq[8], ak[8], av[8];
#pragma unroll
    for (int i = 0; i < 8; ++i) { aq[i] = 0.f; ak[i] = 0.f; av[i] = 0.f; }

#pragma unroll 4
    for (int c = 0; c < 64; ++c) {
        const float xv = xn[c * 64 + n];
#pragma unroll
        for (int i = 0; i < 8; ++i) {
            aq[i] += wq[(d0 + i) * 64 + c] * xv;
            ak[i] += wk[(d0 + i) * 64 + c] * xv;
            av[i] += wv[(d0 + i) * 64 + c] * xv;
        }
    }

    const float QS = 0.18033688011112042f;  // 0.125 * log2(e): exp2-domain logits
    const int m = n0 + n;
    u16x8 qv, kv, vb;
#pragma unroll
    for (int i = 0; i < 8; ++i) {
        qv[i] = f2bf((aq[i] + bq[d0 + i]) * QS);
        kv[i] = f2bf(ak[i] + bk[d0 + i]);
        vb[i] = f2bf(av[i] + bv[d0 + i]);
    }
    // Q: [n][d] row store (16B)
    *(u16x8*)(Qt + ((size_t)(b * N_ + m)) * 64 + d0) = qv;
    // K: direct frag store
    {
        const int kc = dblk >> 1, h = dblk & 1, mt = m >> 5;
        *(u16x8*)(Kf + ((size_t)((b * 128 + mt) * 4 + kc)) * 512
                     + (h * 32 + (m & 31)) * 8) = kv;
    }
    // V: swizzled LDS stage
    *(u16x8*)(vs + n * 128 + ((dblk * 16) ^ ((n & 7) << 4))) = vb;
    __syncthreads();

    // ---- Phase C: frag-ordered Vf copyout (one 16B store per thread) ----
    {
        const int mc_l = t >> 7;            // 0..3
        const int dt   = (t >> 6) & 1;
        const int lp   = t & 63;
        const int hp   = lp >> 5;
        const int dcol = (lp & 31) + dt * 32;
        const int cbase = (dcol & ~7) * 2;
        const int clow  = (dcol & 7) * 2;
        u16x8 tmp;
#pragma unroll
        for (int j = 0; j < 8; ++j) {
            const int ml = mc_l * 16 + hp * 8 + j;   // ml&7 == j
            tmp[j] = *(const unsigned short*)(
                vs + ml * 128 + (cbase ^ (j << 4)) + clow);
        }
        *(u16x8*)(Vf + ((size_t)((b * 256 + (n0 >> 4) + mc_l) * 2 + dt)) * 512
                     + lp * 8) = tmp;
    }
}

// ---------------------------------------------------------------------------
// Kernel 3: attention + fused projection; 8 waves, barrier-free main loop.
// grid = 256 blocks (b = bid&3, qc = bid>>2: 64 q-rows), 512 thr (8 waves).
// Wave wvu: ALL 64 q-rows (dual subtile) x m-eighth [wvu*512, +512) via a
// PRIVATE 16KB dbuf stream (tile 32m: K 4KB | V 4KB). No block barriers in
// the loop; per-wave s_waitcnt vmcnt(0). Epilogue: two-stage f32 LDS merge
// (waves 0-3 write, 4-7 add), normalize -> atile, 512-thr projection.
// LDS 128KB -> 1 block/CU, 8 waves = 2/SIMD.
// ---------------------------------------------------------------------------
__global__ __launch_bounds__(512, 2)
void attn_kernel(const unsigned short* __restrict__ Qt,
                 const unsigned short* __restrict__ Kf,
                 const unsigned short* __restrict__ Vf,
                 const float* __restrict__ wo, const float* __restrict__ bo,
                 float* __restrict__ out) {
    __shared__ __align__(16) char smem[131072];
    const int tid  = threadIdx.x;
    const int lane = tid & 63;
    const int wvu  = __builtin_amdgcn_readfirstlane(tid >> 6);   // m-eighth 0..7
    const int c    = lane & 31;
    const int h    = lane >> 5;
    const int bid  = blockIdx.x;
    const int b    = bid & 3;
    const int qc   = bid >> 2;
    const int n0   = qc * 64;

    // Q B-frags for both 32-row subtiles (same q-rows for all 8 waves)
    const unsigned short* qp = Qt + (size_t)(b * N_ + n0 + c) * 64 + h * 8;
    bf16x8 qa0[4], qa1[4];
#pragma unroll
    for (int kc = 0; kc < 4; ++kc) {
        qa0[kc] = *(const bf16x8*)(qp + kc * 16);
        qa1[kc] = *(const bf16x8*)(qp + 32 * 64 + kc * 16);
    }

    f32x16 o00, o01, o10, o11;
#pragma unroll
    for (int i = 0; i < 16; ++i) { o00[i] = 0.f; o01[i] = 0.f; o10[i] = 0.f; o11[i] = 0.f; }
    float lsA0 = 0.f, lsA1 = 0.f, lsB0 = 0.f, lsB1 = 0.f;

    const int lof = lane * 16;
    char* sbase = smem + wvu * 16384;   // private stream: 2 x 8KB (K 4K | V 4K)
    // m-eighth = 512 m = 16 mt (64KB in Kf) = 32 mc (64KB in Vf)
    const char* kTn = (const char*)Kf + (size_t)b * 524288 + (size_t)wvu * 65536;
    const char* vTn = (const char*)Vf + (size_t)b * 524288 + (size_t)wvu * 65536;

    // ---- prologue: stage tile 0 into buf0 (8 x 1KB chunks) ----
#pragma unroll
    for (int j = 0; j < 4; ++j) {
        gload16(kTn + j * 1024 + lof, sbase + j * 1024);
        gload16(vTn + j * 1024 + lof, sbase + 4096 + j * 1024);
    }
    asm volatile("s_waitcnt vmcnt(0)" ::: "memory");
    __builtin_amdgcn_sched_barrier(0);

    for (int t = 0; t < 16; ++t) {
        char* buf = sbase + ((t & 1) << 13);
        // ---- issue next-tile async stage into the other buffer ----
        if (t + 1 < 16) {
            kTn += 4096;
            vTn += 4096;
            char* dst = sbase + (((t & 1) ^ 1) << 13);
#pragma unroll
            for (int j = 0; j < 4; ++j) {
                gload16(kTn + j * 1024 + lof, dst + j * 1024);
                gload16(vTn + j * 1024 + lof, dst + 4096 + j * 1024);
            }
        }

        // ---- compute current 32-m tile, dual-subtile (r16 body) ----
        const char* kb = buf + lof;
        bf16x8 kf0 = *(const bf16x8*)(kb);
        bf16x8 kf1 = *(const bf16x8*)(kb + 1024);
        bf16x8 kf2 = *(const bf16x8*)(kb + 2048);
        bf16x8 kf3 = *(const bf16x8*)(kb + 3072);
        f32x16 sa0, sa1;
#pragma unroll
        for (int i = 0; i < 16; ++i) { sa0[i] = 0.f; sa1[i] = 0.f; }
        sa0 = __builtin_amdgcn_mfma_f32_32x32x16_bf16(kf0, qa0[0], sa0, 0, 0, 0);
        sa1 = __builtin_amdgcn_mfma_f32_32x32x16_bf16(kf0, qa1[0], sa1, 0, 0, 0);
        sa0 = __builtin_amdgcn_mfma_f32_32x32x16_bf16(kf1, qa0[1], sa0, 0, 0, 0);
        sa1 = __builtin_amdgcn_mfma_f32_32x32x16_bf16(kf1, qa1[1], sa1, 0, 0, 0);
        sa0 = __builtin_amdgcn_mfma_f32_32x32x16_bf16(kf2, qa0[2], sa0, 0, 0, 0);
        sa1 = __builtin_amdgcn_mfma_f32_32x32x16_bf16(kf2, qa1[2], sa1, 0, 0, 0);
        sa0 = __builtin_amdgcn_mfma_f32_32x32x16_bf16(kf3, qa0[3], sa0, 0, 0, 0);
        sa1 = __builtin_amdgcn_mfma_f32_32x32x16_bf16(kf3, qa1[3], sa1, 0, 0, 0);

        // P = exp2(S^T) both subtiles; 4 independent sum chains
#pragma unroll
        for (int i = 0; i < 16; i += 2) {
            float pA0 = fast_exp2(sa0[i]);
            float pA1 = fast_exp2(sa0[i + 1]);
            float pB0 = fast_exp2(sa1[i]);
            float pB1 = fast_exp2(sa1[i + 1]);
            sa0[i] = pA0; sa0[i + 1] = pA1;
            sa1[i] = pB0; sa1[i + 1] = pB1;
            lsA0 += pA0; lsA1 += pA1;
            lsB0 += pB0; lsB1 += pB1;
        }
        // pack both subtiles to bf16 pairs and swap halves
        unsigned dwa[8], dwb[8];
#pragma unroll
        for (int i = 0; i < 8; ++i) {
            asm("v_cvt_pk_bf16_f32 %0, %1, %2"
                : "=v"(dwa[i]) : "v"(sa0[2 * i]), "v"(sa0[2 * i + 1]));
            asm("v_cvt_pk_bf16_f32 %0, %1, %2"
                : "=v"(dwb[i]) : "v"(sa1[2 * i]), "v"(sa1[2 * i + 1]));
        }
        asm("v_permlane32_swap_b32 %0, %1" : "+v"(dwa[0]), "+v"(dwa[2]));
        asm("v_permlane32_swap_b32 %0, %1" : "+v"(dwa[1]), "+v"(dwa[3]));
        asm("v_permlane32_swap_b32 %0, %1" : "+v"(dwa[4]), "+v"(dwa[6]));
        asm("v_permlane32_swap_b32 %0, %1" : "+v"(dwa[5]), "+v"(dwa[7]));
        asm("v_permlane32_swap_b32 %0, %1" : "+v"(dwb[0]), "+v"(dwb[2]));
        asm("v_permlane32_swap_b32 %0, %1" : "+v"(dwb[1]), "+v"(dwb[3]));
        asm("v_permlane32_swap_b32 %0, %1" : "+v"(dwb[4]), "+v"(dwb[6]));
        asm("v_permlane32_swap_b32 %0, %1" : "+v"(dwb[5]), "+v"(dwb[7]));
        bf16x8 pa0 = __builtin_bit_cast(bf16x8, (u32x4){dwa[0], dwa[1], dwa[2], dwa[3]});
        bf16x8 pa1 = __builtin_bit_cast(bf16x8, (u32x4){dwa[4], dwa[5], dwa[6], dwa[7]});
        bf16x8 pb0 = __builtin_bit_cast(bf16x8, (u32x4){dwb[0], dwb[1], dwb[2], dwb[3]});
        bf16x8 pb1 = __builtin_bit_cast(bf16x8, (u32x4){dwb[4], dwb[5], dwb[6], dwb[7]});

        // PV both subtiles from the SAME V frag reads (4 acc chains)
        const char* vbp = buf + 4096 + lof;
        bf16x8 vf0 = *(const bf16x8*)(vbp);
        bf16x8 vf1 = *(const bf16x8*)(vbp + 1024);
        bf16x8 vf2 = *(const bf16x8*)(vbp + 2048);
        bf16x8 vf3 = *(const bf16x8*)(vbp + 3072);
        o00 = __builtin_amdgcn_mfma_f32_32x32x16_bf16(vf0, pa0, o00, 0, 0, 0);
        o10 = __builtin_amdgcn_mfma_f32_32x32x16_bf16(vf0, pb0, o10, 0, 0, 0);
        o01 = __builtin_amdgcn_mfma_f32_32x32x16_bf16(vf1, pa0, o01, 0, 0, 0);
        o11 = __builtin_amdgcn_mfma_f32_32x32x16_bf16(vf1, pb0, o11, 0, 0, 0);
        o00 = __builtin_amdgcn_mfma_f32_32x32x16_bf16(vf2, pa1, o00, 0, 0, 0);
        o10 = __builtin_amdgcn_mfma_f32_32x32x16_bf16(vf2, pb1, o10, 0, 0, 0);
        o01 = __builtin_amdgcn_mfma_f32_32x32x16_bf16(vf3, pa1, o01, 0, 0, 0);
        o11 = __builtin_amdgcn_mfma_f32_32x32x16_bf16(vf3, pb1, o11, 0, 0, 0);

        // per-wave drain of the next tile's staging (NO block barrier)
        asm volatile("s_waitcnt vmcnt(0)" ::: "memory");
        __builtin_amdgcn_sched_barrier(0);
    }

    // per-wave rowsums (col q = own half + other half), per subtile
    float lsA = lsA0 + lsA1;
    float lsB = lsB0 + lsB1;
    float rsA = lsA + __shfl_xor(lsA, 32);
    float rsB = lsB + __shfl_xor(lsB, 32);

    // ---- epilogue: two-stage f32 merge, normalize, in-block projection ----
    __syncthreads();                          // all streams dead; LDS reusable
    float* lsm   = (float*)(smem + 65536);    // [8 wave][64 q] (dead stream)
    float* atile = (float*)(smem + 68608);    // [64 d][65] f32
    if (wvu < 4) {                            // stage A: waves 0-3 write
        float* mrg = (float*)(smem + wvu * 16384);
#pragma unroll
        for (int r = 0; r < 16; ++r) {
            const int row = (r & 3) + 8 * (r >> 2) + 4 * h;
            mrg[row * 64 + c]             = o00[r];
            mrg[(row + 32) * 64 + c]      = o01[r];
            mrg[row * 64 + 32 + c]        = o10[r];
            mrg[(row + 32) * 64 + 32 + c] = o11[r];
        }
    }
    if (h == 0) {
        lsm[wvu * 64 + c]      = rsA;
        lsm[wvu * 64 + 32 + c] = rsB;
    }
    __syncthreads();
    if (wvu >= 4) {                           // stage B: waves 4-7 add
        float* mrg = (float*)(smem + (wvu - 4) * 16384);
#pragma unroll
        for (int r = 0; r < 16; ++r) {
            const int row = (r & 3) + 8 * (r >> 2) + 4 * h;
            mrg[row * 64 + c]             += o00[r];
            mrg[(row + 32) * 64 + c]      += o01[r];
            mrg[row * 64 + 32 + c]        += o10[r];
            mrg[(row + 32) * 64 + 32 + c] += o11[r];
        }
    }
    __syncthreads();
    if (wvu < 4) {   // quadrant merge of the 4 buffers + normalize -> atile
        const int dh = wvu >> 1, qh = wvu & 1;
        const int qq = qh * 32 + c;
        float lt = 0.f;
#pragma unroll
        for (int k = 0; k < 8; ++k) lt += lsm[k * 64 + qq];
        const float inv = 1.f / lt;
        const float* m0 = (const float*)smem;
#pragma unroll
        for (int r = 0; r < 16; ++r) {
            const int row = dh * 32 + (r & 3) + 8 * (r >> 2) + 4 * h;
            const int idx = row * 64 + qq;
            float sum = (m0[idx] + m0[4096 + idx])
                      + (m0[8192 + idx] + m0[12288 + idx]);
            atile[row * 65 + qq] = sum * inv;
        }
    }
    __syncthreads();
    {   // projection: 512 thr; thread (n = tid&63, 8 e's)
        const int n  = tid & 63;
        const int e0 = (tid >> 6) * 8;
        float acc[8];
#pragma unroll
        for (int i = 0; i < 8; ++i) acc[i] = bo[e0 + i];
#pragma unroll 8
        for (int d = 0; d < 64; ++d) {
            const float xv = atile[d * 65 + n];
#pragma unroll
            for (int i = 0; i < 8; ++i) acc[i] += wo[(e0 + i) * 64 + d] * xv;
        }
#pragma unroll
        for (int i = 0; i < 8; ++i)
            out[((size_t)(b * 64 + e0 + i) << 12) + n0 + n] = acc[i];
    }
}

// ---------------------------------------------------------------------------
extern "C" void kernel_launch(void* const* d_in, const int* in_sizes, int n_in,
                              void* d_out, int out_size, void* d_ws, size_t ws_size,
                              hipStream_t stream) {
    const float* x   = (const float*)d_in[0];
    const float* gnw = (const float*)d_in[1];
    const float* gnb = (const float*)d_in[2];
    const float* wq  = (const float*)d_in[3];
    const float* bq  = (const float*)d_in[4];
    const float* wk  = (const float*)d_in[5];
    const float* bk  = (const float*)d_in[6];
    const float* wv  = (const float*)d_in[7];
    const float* bv  = (const float*)d_in[8];
    const float* wo  = (const float*)d_in[9];
    const float* bo  = (const float*)d_in[10];
    float* out = (float*)d_out;

    char* wsb = (char*)d_ws;
    float*          stats = (float*)wsb;                                  //   2 KB
    unsigned short* Qt    = (unsigned short*)(wsb + 2048);                //   2 MB
    unsigned short* Kf    = (unsigned short*)(wsb + 2048 + 2097152);      //   2 MB
    unsigned short* Vf    = (unsigned short*)(wsb + 2048 + 2 * 2097152);  //   2 MB

    gn_stats_kernel<<<dim3(B_ * C_), dim3(1024), 0, stream>>>(x, stats);
    gn_qkv_kernel<<<dim3(B_ * 64), dim3(512), 0, stream>>>(
        x, stats, gnw, gnb, wq, bq, wk, bk, wv, bv, Qt, Kf, Vf);
    attn_kernel<<<dim3(B_ * 64), dim3(512), 0, stream>>>(
        Qt, Kf, Vf, wo, bo, out);
}